// Round 1
// baseline (3017.130 us; speedup 1.0000x reference)
//
#include <hip/hip_runtime.h>
#include <stdint.h>

#define BB 8
#define TTN 4096
#define CCH 32
#define NTILES 128           // TTN/32
#define HALFN 67108864u      // 2^26 = total mask elements / 2
#define KEEP_LT 6710887u     // keep iff (bits>>9) < this  <=> uniform < 0.8f

// RNG variant: 0 = partitionable (o0^o1), 1 = legacy split-halves, 2 = partitionable o0
#ifndef RNG_VARIANT
#define RNG_VARIANT 0
#endif

__device__ __forceinline__ uint32_t rotl32(uint32_t x, int r) {
    return (x << r) | (x >> (32 - r));
}

// threefry2x32, 20 rounds, key fixed to (0, 42) == jax.random.key(42)
__device__ __forceinline__ void threefry2x32_k042(uint32_t x0, uint32_t x1,
                                                  uint32_t& o0, uint32_t& o1) {
    const uint32_t k0 = 0u, k1 = 42u;
    const uint32_t k2 = 0u ^ 42u ^ 0x1BD11BDAu;
    x0 += k0; x1 += k1;
#define TFR(r) { x0 += x1; x1 = rotl32(x1, (r)); x1 ^= x0; }
    TFR(13) TFR(15) TFR(26) TFR(6)
    x0 += k1; x1 += k2 + 1u;
    TFR(17) TFR(29) TFR(16) TFR(24)
    x0 += k2; x1 += k0 + 2u;
    TFR(13) TFR(15) TFR(26) TFR(6)
    x0 += k0; x1 += k1 + 3u;
    TFR(17) TFR(29) TFR(16) TFR(24)
    x0 += k1; x1 += k2 + 4u;
    TFR(13) TFR(15) TFR(26) TFR(6)
    x0 += k2; x1 += k0 + 5u;
#undef TFR
    o0 = x0; o1 = x1;
}

// random 32 bits for flat mask element idx (< 2^27, so hi32(idx)==0)
__device__ __forceinline__ uint32_t mask_bits(uint32_t idx) {
#if RNG_VARIANT == 0
    uint32_t o0, o1; threefry2x32_k042(0u, idx, o0, o1); return o0 ^ o1;
#elif RNG_VARIANT == 1
    uint32_t lo = (idx < HALFN) ? idx : (idx - HALFN);
    uint32_t o0, o1; threefry2x32_k042(lo, lo + HALFN, o0, o1);
    return (idx < HALFN) ? o0 : o1;
#else
    uint32_t o0, o1; threefry2x32_k042(0u, idx, o0, o1); return o0;
#endif
}

// ---------------- projections: q = (x @ Wq^T) * 1/sqrt(32), k, v ----------------
__global__ __launch_bounds__(256) void proj_qkv(const float* __restrict__ x,
                                                const float* __restrict__ Wq,
                                                const float* __restrict__ Wk,
                                                const float* __restrict__ Wv,
                                                float* __restrict__ Q,
                                                float* __restrict__ K,
                                                float* __restrict__ V) {
    __shared__ float sW[3][CCH * CCH];
    const int tid = threadIdx.x;
    for (int i = tid; i < CCH * CCH; i += 256) {
        sW[0][i] = Wq[i]; sW[1][i] = Wk[i]; sW[2][i] = Wv[i];
    }
    __syncthreads();
    const int row = blockIdx.x * 256 + tid;     // b*T + t, grid covers B*T
    const float4* xp = reinterpret_cast<const float4*>(x + (size_t)row * CCH);
    float xr[CCH];
    #pragma unroll
    for (int i = 0; i < 8; ++i) {
        float4 t4 = xp[i];
        xr[4*i] = t4.x; xr[4*i+1] = t4.y; xr[4*i+2] = t4.z; xr[4*i+3] = t4.w;
    }
    const float scale = 0.17677669529663687f;   // 1/sqrt(32)
    for (int mtx = 0; mtx < 3; ++mtx) {
        float* op_base = (mtx == 0) ? Q : ((mtx == 1) ? K : V);
        float o[CCH];
        #pragma unroll
        for (int d = 0; d < CCH; ++d) {
            float s0 = 0.f, s1 = 0.f, s2 = 0.f, s3 = 0.f;
            #pragma unroll
            for (int c = 0; c < CCH; c += 4) {
                s0 += xr[c]   * sW[mtx][d*CCH + c];
                s1 += xr[c+1] * sW[mtx][d*CCH + c+1];
                s2 += xr[c+2] * sW[mtx][d*CCH + c+2];
                s3 += xr[c+3] * sW[mtx][d*CCH + c+3];
            }
            o[d] = (s0 + s1) + (s2 + s3);
            if (mtx == 0) o[d] *= scale;
        }
        float4* op = reinterpret_cast<float4*>(op_base + (size_t)row * CCH);
        #pragma unroll
        for (int i = 0; i < 8; ++i)
            op[i] = make_float4(o[4*i], o[4*i+1], o[4*i+2], o[4*i+3]);
    }
}

// ---------------- fused causal attention + exact JAX dropout ----------------
// One wave per (batch-pair, 32-row tile). lane<32 -> batch bp, lane>=32 -> bp+4.
// Each lane owns one q row (32 VGPRs) and an fp32 acc[32]; online softmax;
// dropout applied to numerator only: out = sum(keep*p*v) / (0.8 * sum(p)).
__global__ __launch_bounds__(64) void attn_fused(const float* __restrict__ Q,
                                                 const float* __restrict__ K,
                                                 const float* __restrict__ V,
                                                 float* __restrict__ out) {
    const int j = blockIdx.x;                   // 0..511
    const int bp = j & 3;                       // batch pair: (bp, bp+4)
    const int tile = NTILES - 1 - (j >> 2);     // largest-work-first dispatch
    const int lane = threadIdx.x;               // 0..63
    const int half = lane >> 5;
    const int r = lane & 31;
    const int t = tile * 32 + r;
    const int b = bp + 4 * half;

    const size_t rowoff = ((size_t)b * TTN + t) * CCH;
    const float4* qp = reinterpret_cast<const float4*>(Q + rowoff);
    float q[CCH];
    #pragma unroll
    for (int i = 0; i < 8; ++i) {
        float4 t4 = qp[i];
        q[4*i] = t4.x; q[4*i+1] = t4.y; q[4*i+2] = t4.z; q[4*i+3] = t4.w;
    }
    float acc[CCH];
    #pragma unroll
    for (int i = 0; i < CCH; ++i) acc[i] = 0.f;
    float m = -INFINITY, l = 0.f;

    const uint32_t idx_base = (uint32_t)b * 16777216u + (uint32_t)t * 4096u;
    const float* kbase = K + (size_t)b * TTN * CCH;
    const float* vbase = V + (size_t)b * TTN * CCH;
    const int send = tile * 32 + 31;

    for (int s = 0; s <= send; ++s) {
        const float4* kp = reinterpret_cast<const float4*>(kbase + (size_t)s * CCH);
        float kr[CCH];
        #pragma unroll
        for (int i = 0; i < 8; ++i) {
            float4 t4 = kp[i];
            kr[4*i]=t4.x; kr[4*i+1]=t4.y; kr[4*i+2]=t4.z; kr[4*i+3]=t4.w;
        }
        float d0=0.f, d1=0.f, d2=0.f, d3=0.f;
        #pragma unroll
        for (int c = 0; c < CCH; c += 4) {
            d0 += q[c]   * kr[c];
            d1 += q[c+1] * kr[c+1];
            d2 += q[c+2] * kr[c+2];
            d3 += q[c+3] * kr[c+3];
        }
        const float score = (d0 + d1) + (d2 + d3);   // scale folded into q

        const float4* vp = reinterpret_cast<const float4*>(vbase + (size_t)s * CCH);
        float vr[CCH];
        #pragma unroll
        for (int i = 0; i < 8; ++i) {
            float4 t4 = vp[i];
            vr[4*i]=t4.x; vr[4*i+1]=t4.y; vr[4*i+2]=t4.z; vr[4*i+3]=t4.w;
        }

        const uint32_t bits = mask_bits(idx_base + (uint32_t)s);
        const bool keep = (bits >> 9) < KEEP_LT;

        if (s <= t) {
            if (score > m) {
                const float corr = __expf(m - score);  // exp(-inf)=0 on first hit
                m = score;
                l *= corr;
                #pragma unroll
                for (int c = 0; c < CCH; ++c) acc[c] *= corr;
            }
            const float p = __expf(score - m);
            l += p;
            const float pk = keep ? p : 0.f;
            #pragma unroll
            for (int c = 0; c < CCH; ++c) acc[c] += pk * vr[c];
        }
    }

    const float inv = 1.0f / (0.8f * l);
    float4* op = reinterpret_cast<float4*>(out + rowoff);
    #pragma unroll
    for (int i = 0; i < 8; ++i)
        op[i] = make_float4(acc[4*i]*inv, acc[4*i+1]*inv, acc[4*i+2]*inv, acc[4*i+3]*inv);
}

extern "C" void kernel_launch(void* const* d_in, const int* in_sizes, int n_in,
                              void* d_out, int out_size, void* d_ws, size_t ws_size,
                              hipStream_t stream) {
    const float* x  = (const float*)d_in[0];
    const float* Wq = (const float*)d_in[1];
    const float* Wk = (const float*)d_in[2];
    const float* Wv = (const float*)d_in[3];
    float* outp = (float*)d_out;

    // workspace: Q | K | V  (3 * 8*4096*32 floats = 12 MiB)
    float* Qw = (float*)d_ws;
    float* Kw = Qw + (size_t)BB * TTN * CCH;
    float* Vw = Kw + (size_t)BB * TTN * CCH;

    proj_qkv<<<(BB * TTN) / 256, 256, 0, stream>>>(x, Wq, Wk, Wv, Qw, Kw, Vw);
    attn_fused<<<4 * NTILES, 64, 0, stream>>>(Qw, Kw, Vw, outp);
}

// Round 2
// 1145.942 us; speedup vs baseline: 2.6329x; 2.6329x over previous
//
#include <hip/hip_runtime.h>
#include <stdint.h>

#define BB 8
#define TTN 4096
#define CCH 32
#define KEEP_LT 6710887u     // keep iff (bits>>9) < this  <=> uniform < 0.8f

__device__ __forceinline__ uint32_t rotl32(uint32_t x, int r) {
    return (x << r) | (x >> (32 - r));
}

// threefry2x32, 20 rounds, key fixed to (0, 42) == jax.random.key(42)
__device__ __forceinline__ void threefry2x32_k042(uint32_t x0, uint32_t x1,
                                                  uint32_t& o0, uint32_t& o1) {
    const uint32_t k0 = 0u, k1 = 42u;
    const uint32_t k2 = 0u ^ 42u ^ 0x1BD11BDAu;
    x0 += k0; x1 += k1;
#define TFR(r) { x0 += x1; x1 = rotl32(x1, (r)); x1 ^= x0; }
    TFR(13) TFR(15) TFR(26) TFR(6)
    x0 += k1; x1 += k2 + 1u;
    TFR(17) TFR(29) TFR(16) TFR(24)
    x0 += k2; x1 += k0 + 2u;
    TFR(13) TFR(15) TFR(26) TFR(6)
    x0 += k0; x1 += k1 + 3u;
    TFR(17) TFR(29) TFR(16) TFR(24)
    x0 += k1; x1 += k2 + 4u;
    TFR(13) TFR(15) TFR(26) TFR(6)
    x0 += k2; x1 += k0 + 5u;
#undef TFR
    o0 = x0; o1 = x1;
}

// partitionable threefry: bits(i) = o0^o1 of threefry(key42, (0, i))
__device__ __forceinline__ uint32_t mask_bits(uint32_t idx) {
    uint32_t o0, o1; threefry2x32_k042(0u, idx, o0, o1); return o0 ^ o1;
}

// ---------------- projections: q = (x @ Wq^T) * 1/sqrt(32), k, v ----------------
__global__ __launch_bounds__(256) void proj_qkv(const float* __restrict__ x,
                                                const float* __restrict__ Wq,
                                                const float* __restrict__ Wk,
                                                const float* __restrict__ Wv,
                                                float* __restrict__ Q,
                                                float* __restrict__ K,
                                                float* __restrict__ V) {
    __shared__ float sW[3][CCH * CCH];
    const int tid = threadIdx.x;
    for (int i = tid; i < CCH * CCH; i += 256) {
        sW[0][i] = Wq[i]; sW[1][i] = Wk[i]; sW[2][i] = Wv[i];
    }
    __syncthreads();
    const int row = blockIdx.x * 256 + tid;     // b*T + t
    const float4* xp = reinterpret_cast<const float4*>(x + (size_t)row * CCH);
    float xr[CCH];
    #pragma unroll
    for (int i = 0; i < 8; ++i) {
        float4 t4 = xp[i];
        xr[4*i] = t4.x; xr[4*i+1] = t4.y; xr[4*i+2] = t4.z; xr[4*i+3] = t4.w;
    }
    const float scale = 0.17677669529663687f;   // 1/sqrt(32)
    for (int mtx = 0; mtx < 3; ++mtx) {
        float* op_base = (mtx == 0) ? Q : ((mtx == 1) ? K : V);
        float o[CCH];
        #pragma unroll
        for (int d = 0; d < CCH; ++d) {
            float s0 = 0.f, s1 = 0.f, s2 = 0.f, s3 = 0.f;
            #pragma unroll
            for (int c = 0; c < CCH; c += 4) {
                s0 += xr[c]   * sW[mtx][d*CCH + c];
                s1 += xr[c+1] * sW[mtx][d*CCH + c+1];
                s2 += xr[c+2] * sW[mtx][d*CCH + c+2];
                s3 += xr[c+3] * sW[mtx][d*CCH + c+3];
            }
            o[d] = (s0 + s1) + (s2 + s3);
            if (mtx == 0) o[d] *= scale;
        }
        float4* op = reinterpret_cast<float4*>(op_base + (size_t)row * CCH);
        #pragma unroll
        for (int i = 0; i < 8; ++i)
            op[i] = make_float4(o[4*i], o[4*i+1], o[4*i+2], o[4*i+3]);
    }
}

// ---------------- fused causal attention + exact JAX dropout, split-s ----------------
// Block = (batch b, 64-row q-tile). 8 waves split the s-range into equal chunks
// of 8*(tile+1); each wave builds a partial (m, l, acc[32]) per q-row (one row
// per lane). Waves 1..7 publish partials to LDS; wave 0 merges and writes out.
// Dropout exact-JAX: keep iff threefry-partitionable bits(idx)>>9 < 0.8*2^23.
__global__ __launch_bounds__(512, 4) void attn_fused(const float* __restrict__ Q,
                                                     const float* __restrict__ K,
                                                     const float* __restrict__ V,
                                                     float* __restrict__ out) {
    __shared__ float part[7][64][34];           // m, l, acc[32] per (wave-1, lane)

    const int j = blockIdx.x;                   // 0..511, paired big/small tiles
    int tile, b;
    if (j < 256) { tile = 63 - (j >> 3); b = j & 7; }
    else         { tile = (j - 256) >> 3; b = j & 7; }
    const int w = threadIdx.x >> 6;             // wave 0..7
    const int lane = threadIdx.x & 63;
    const int t = tile * 64 + lane;             // this lane's q row

    const size_t rowoff = ((size_t)b * TTN + t) * CCH;
    const float4* qp = reinterpret_cast<const float4*>(Q + rowoff);
    float q[CCH];
    #pragma unroll
    for (int i = 0; i < 8; ++i) {
        float4 t4 = qp[i];
        q[4*i] = t4.x; q[4*i+1] = t4.y; q[4*i+2] = t4.z; q[4*i+3] = t4.w;
    }
    float acc[CCH];
    #pragma unroll
    for (int i = 0; i < CCH; ++i) acc[i] = 0.f;
    float m = -INFINITY, l = 0.f;

    const uint32_t idx_base = ((uint32_t)b << 24) + ((uint32_t)t << 12);
    const float* kbase = K + (size_t)b * TTN * CCH;
    const float* vbase = V + (size_t)b * TTN * CCH;

    const int chunk = 8 * (tile + 1);           // (64*(tile+1)) / 8 waves, exact
    const int s0 = w * chunk;
    const int s1 = s0 + chunk;
    const int umend = min(s1, tile * 64);       // s < tile*64 is valid for all lanes

#define ATT_BODY(VALID_EXPR)                                                   \
    {                                                                          \
        const float4* kp = reinterpret_cast<const float4*>(kbase + (size_t)s * CCH); \
        float kr[CCH];                                                         \
        _Pragma("unroll")                                                      \
        for (int i = 0; i < 8; ++i) {                                          \
            float4 t4 = kp[i];                                                 \
            kr[4*i]=t4.x; kr[4*i+1]=t4.y; kr[4*i+2]=t4.z; kr[4*i+3]=t4.w;      \
        }                                                                      \
        float d0=0.f, d1=0.f, d2=0.f, d3=0.f;                                  \
        _Pragma("unroll")                                                      \
        for (int c = 0; c < CCH; c += 4) {                                     \
            d0 += q[c]   * kr[c];                                              \
            d1 += q[c+1] * kr[c+1];                                            \
            d2 += q[c+2] * kr[c+2];                                            \
            d3 += q[c+3] * kr[c+3];                                            \
        }                                                                      \
        const float score = (d0 + d1) + (d2 + d3);                             \
        const float4* vp = reinterpret_cast<const float4*>(vbase + (size_t)s * CCH); \
        float vr[CCH];                                                         \
        _Pragma("unroll")                                                      \
        for (int i = 0; i < 8; ++i) {                                          \
            float4 t4 = vp[i];                                                 \
            vr[4*i]=t4.x; vr[4*i+1]=t4.y; vr[4*i+2]=t4.z; vr[4*i+3]=t4.w;      \
        }                                                                      \
        const uint32_t bits = mask_bits(idx_base + (uint32_t)s);               \
        const bool keep = (bits >> 9) < KEEP_LT;                               \
        const bool valid = (VALID_EXPR);                                       \
        if (valid && score > m + 8.0f) {        /* deferred-max rescale */     \
            const float corr = __expf(m - score);                              \
            m = score; l *= corr;                                              \
            _Pragma("unroll")                                                  \
            for (int c = 0; c < CCH; ++c) acc[c] *= corr;                      \
        }                                                                      \
        const float p = valid ? __expf(score - m) : 0.f;                       \
        l += p;                                                                \
        const float pk = keep ? p : 0.f;                                       \
        _Pragma("unroll")                                                      \
        for (int c = 0; c < CCH; ++c) acc[c] = fmaf(pk, vr[c], acc[c]);        \
    }

    for (int s = s0; s < umend; ++s) ATT_BODY(true)                 // unmasked bulk
    for (int s = max(s0, tile * 64); s < s1; ++s) ATT_BODY(s <= t)  // causal tail
#undef ATT_BODY

    if (w > 0) {
        part[w-1][lane][0] = m;
        part[w-1][lane][1] = l;
        #pragma unroll
        for (int c = 0; c < CCH; ++c) part[w-1][lane][2+c] = acc[c];
    }
    __syncthreads();
    if (w == 0) {
        for (int pw = 0; pw < 7; ++pw) {
            const float mw = part[pw][lane][0];
            const float lw = part[pw][lane][1];
            if (lw > 0.f) {
                const float mn = fmaxf(m, mw);
                const float ca = __expf(m - mn);
                const float cb = __expf(mw - mn);
                l = l * ca + lw * cb;
                #pragma unroll
                for (int c = 0; c < CCH; ++c)
                    acc[c] = acc[c] * ca + part[pw][lane][2+c] * cb;
                m = mn;
            }
        }
        const float inv = 1.0f / (0.8f * l);
        float4* op = reinterpret_cast<float4*>(out + rowoff);
        #pragma unroll
        for (int i = 0; i < 8; ++i)
            op[i] = make_float4(acc[4*i]*inv, acc[4*i+1]*inv,
                                acc[4*i+2]*inv, acc[4*i+3]*inv);
    }
}

extern "C" void kernel_launch(void* const* d_in, const int* in_sizes, int n_in,
                              void* d_out, int out_size, void* d_ws, size_t ws_size,
                              hipStream_t stream) {
    const float* x  = (const float*)d_in[0];
    const float* Wq = (const float*)d_in[1];
    const float* Wk = (const float*)d_in[2];
    const float* Wv = (const float*)d_in[3];
    float* outp = (float*)d_out;

    float* Qw = (float*)d_ws;
    float* Kw = Qw + (size_t)BB * TTN * CCH;
    float* Vw = Kw + (size_t)BB * TTN * CCH;

    proj_qkv<<<(BB * TTN) / 256, 256, 0, stream>>>(x, Wq, Wk, Wv, Qw, Kw, Vw);
    attn_fused<<<512, 512, 0, stream>>>(Qw, Kw, Vw, outp);
}